// Round 7
// baseline (35.133 us; speedup 1.0000x reference)
//
#include <hip/hip_runtime.h>
#include <math.h>

// DeepFeatureLoss: B=2, N=4096, D=32, fp32 in/out.
// out[0..1] = ce_loss[b], out[2..3] = reg_loss[b].
//
// ce_i = log(s_f) - t/s_p   (softmax max pinned at 0; both dists <= 0):
//   s_p = sum_j exp(pd_ij), t = sum_j exp(pd_ij)*fd_ij, s_f = sum_j exp(fd_ij)
// exp2 folding: points *PSC, features *FSC, norms *L2E -> bare v_exp_f32;
// t is in log2 units -> *LN2 at finalize.
//
// R7: occupancy push. R4 counters (VALUBusy 6.7%, occ 42%) + weak ILP
// response in R6 say kB is TLP-starved at 4 waves/SIMD. Blocks go
// 512thr->1024thr (16 waves, each wave 16 j-tiles): 2 blocks/CU =
// 32 waves/CU = 8 waves/SIMD (chip max). __launch_bounds__(1024,8)
// caps VGPR at 64 so 8 waves/SIMD actually fit (m69 cliff).
//
// ws (floats): pp1[0,32768) pp2[32768,65536) fragB[65536,196608)
// fragA[196608,327680) regp[327680,335872).

#define NPTS 4096
#define ROWS_TOT 8192
#define DF 32
#define NTILE 512                // 16-row i-tiles across both batches

#define L2E  1.4426950408889634f
#define LN2  0.6931471805599453f
#define FSC  1.6986436f          // sqrt(2*log2e)
#define PSC  240.2244f           // 200*sqrt(log2e)

typedef _Float16 half8 __attribute__((ext_vector_type(8)));
typedef float f4 __attribute__((ext_vector_type(4)));

// ---- kA: prep ----
__global__ void kA_prep(const float* __restrict__ pts,
                        const float* __restrict__ f1g,
                        const float* __restrict__ f2g,
                        float* __restrict__ pp1, float* __restrict__ pp2,
                        _Float16* __restrict__ fragA, _Float16* __restrict__ fragB,
                        float* __restrict__ regp, float* __restrict__ out) {
    const int r = blockIdx.x * 64 + threadIdx.x;     // 0..8191
    if (r < 4) out[r] = 0.0f;
    const int jt = r >> 4;                           // global tile id 0..511
    const int c  = r & 15;                           // row/col within tile

    float n1, n2, reg1, reg2;
    {
        const float4* f2v = (const float4*)(f2g + (size_t)r * DF);
        float vals[32];
        float s = 0.0f;
#pragma unroll
        for (int q = 0; q < 8; ++q) {
            float4 v = f2v[q];
            vals[4*q]=v.x; vals[4*q+1]=v.y; vals[4*q+2]=v.z; vals[4*q+3]=v.w;
            s += v.x*v.x + v.y*v.y + v.z*v.z + v.w*v.w;
        }
        n2 = s;
        reg2 = s - vals[0]*vals[0] - vals[1]*vals[1] - vals[2]*vals[2];
        half8* fv = (half8*)fragB;
#pragma unroll
        for (int kb = 0; kb < 4; ++kb) {             // lane-ordered slot
            half8 h;
#pragma unroll
            for (int i = 0; i < 8; ++i) h[i] = (_Float16)(vals[kb*8+i] * FSC);
            fv[(size_t)jt*64 + kb*16 + c] = h;
        }
    }
    {
        const float4* f1v = (const float4*)(f1g + (size_t)r * DF);
        float vals[32];
        float s = 0.0f;
#pragma unroll
        for (int q = 0; q < 8; ++q) {
            float4 v = f1v[q];
            vals[4*q]=v.x; vals[4*q+1]=v.y; vals[4*q+2]=v.z; vals[4*q+3]=v.w;
            s += v.x*v.x + v.y*v.y + v.z*v.z + v.w*v.w;
        }
        n1 = s;
        reg1 = s - vals[0]*vals[0] - vals[1]*vals[1] - vals[2]*vals[2];
        half8* fv = (half8*)fragA;
#pragma unroll
        for (int kb = 0; kb < 4; ++kb) {
            half8 h;
#pragma unroll
            for (int i = 0; i < 8; ++i) h[i] = (_Float16)(vals[kb*8+i] * FSC);
            fv[(size_t)jt*64 + kb*16 + c] = h;
        }
    }
    const float* pp = pts + (size_t)r * 3;
    const float px = pp[0]*PSC, py = pp[1]*PSC, pz = pp[2]*PSC;
    ((float4*)pp1)[r] = make_float4(px, py, pz, n1 * L2E);
    ((float4*)pp2)[r] = make_float4(px, py, pz, n2 * L2E);
    regp[r] = reg1 + reg2;
}

// ---- kB: one block per i-tile; 16 waves x 16 j-tiles; 8 waves/SIMD ----
__launch_bounds__(1024, 8)
__global__ void kB_main(const float* __restrict__ pp1,
                        const float* __restrict__ pp2,
                        const _Float16* __restrict__ fragA,
                        const _Float16* __restrict__ fragB,
                        const float* __restrict__ regp,
                        const float* __restrict__ wg,
                        float* __restrict__ out) {
    __shared__ float sS[16][16], sT[16][16], sF[16][16];

    const int tid = threadIdx.x;
    const int l = tid & 63, wv = tid >> 6;           // wave 0..15
    const int i_tile = blockIdx.x;                   // 0..511
    const int b = i_tile >> 8;
    const int i0g = i_tile * 16;                     // global row base
    const int lr = l & 15, lk = l >> 4;

    const half8 afrag = ((const half8*)fragA)[(size_t)i_tile * 64 + l];

    const int rbase = i0g + lk * 4;                  // this lane's 4 rows
    const float4 q0 = ((const float4*)pp1)[rbase + 0];
    const float4 q1 = ((const float4*)pp1)[rbase + 1];
    const float4 q2 = ((const float4*)pp1)[rbase + 2];
    const float4 q3 = ((const float4*)pp1)[rbase + 3];
    const f4 qx = {q0.x, q1.x, q2.x, q3.x};
    const f4 qy = {q0.y, q1.y, q2.y, q3.y};
    const f4 qz = {q0.z, q1.z, q2.z, q3.z};
    const f4 qw = {q0.w, q1.w, q2.w, q3.w};

    // wave's j range: frag tile (b*256 + wv*16 + t), rows
    // b*4096 + wv*256 + t*16 + lr, t = 0..15.
    const half8*  fbase = (const half8*)fragB + ((size_t)(b * 256 + wv * 16) * 64 + l);
    const float4* pbase = (const float4*)pp2 + (b * NPTS + wv * 256 + lr);

    f4 sp = {0,0,0,0}, tA = {0,0,0,0}, sf = {0,0,0,0};
    const f4 zero = {0.f, 0.f, 0.f, 0.f};

    half8  bfA = fbase[0];
    float4 pwA = pbase[0];
#pragma unroll
    for (int t = 0; t < 16; ++t) {
        half8  bfN = bfA;
        float4 pwN = pwA;
        if (t < 15) {                                // 1-deep prefetch
            bfN = fbase[(t + 1) * 64];
            pwN = pbase[(t + 1) * 16];
        }
        const f4 cc4 = __builtin_amdgcn_mfma_f32_16x16x32_f16(afrag, bfA, zero, 0, 0, 0);
        const f4 fd = cc4 - qw - pwA.w;              // log2e * fea_dist2 (<=0)
        const f4 dx = qx - pwA.x;
        const f4 dy = qy - pwA.y;
        const f4 dz = qz - pwA.z;
        const f4 s  = dx*dx + dy*dy + dz*dz;         // log2e * |dp|^2
        f4 ep, ef;
#pragma unroll
        for (int e = 0; e < 4; ++e) {
            ep[e] = __builtin_amdgcn_exp2f(-s[e]);   // neg folds into modifier
            ef[e] = __builtin_amdgcn_exp2f(fd[e]);
        }
        sp += ep;
        tA += ep * fd;
        sf += ef;
        bfA = bfN;
        pwA = pwN;
    }

    // reduce over the 16 columns (lane bits 0..3)
#pragma unroll
    for (int m = 1; m < 16; m <<= 1) {
#pragma unroll
        for (int e = 0; e < 4; ++e) {
            sp[e] += __shfl_xor(sp[e], m);
            tA[e] += __shfl_xor(tA[e], m);
            sf[e] += __shfl_xor(sf[e], m);
        }
    }
    if (lr == 0) {
#pragma unroll
        for (int e = 0; e < 4; ++e) {
            sS[wv][lk * 4 + e] = sp[e];
            sT[wv][lk * 4 + e] = tA[e];
            sF[wv][lk * 4 + e] = sf[e];
        }
    }
    __syncthreads();

    if (tid < 16) {
        float sp_ = 0.f, tp_ = 0.f, sf_ = 0.f;
#pragma unroll
        for (int w = 0; w < 16; ++w) {
            sp_ += sS[w][tid];
            tp_ += sT[w][tid];
            sf_ += sF[w][tid];
        }
        const int r = i0g + tid;
        const float ce = __logf(sf_) - (tp_ * LN2) / sp_;
        float contrib = wg[r] * ce;
        float rr = regp[r];
#pragma unroll
        for (int m = 1; m < 16; m <<= 1) {           // lanes 0..15 only
            contrib += __shfl_xor(contrib, m);
            rr      += __shfl_xor(rr, m);
        }
        if (tid == 0) {
            atomicAdd(&out[b],     contrib);
            atomicAdd(&out[2 + b], rr * (1.0f / (29.0f * (float)NPTS)));
        }
    }
}

extern "C" void kernel_launch(void* const* d_in, const int* in_sizes, int n_in,
                              void* d_out, int out_size, void* d_ws, size_t ws_size,
                              hipStream_t stream) {
    const float* pts = (const float*)d_in[0];
    const float* f1  = (const float*)d_in[1];
    const float* f2  = (const float*)d_in[2];
    const float* wg  = (const float*)d_in[3];
    float* out = (float*)d_out;

    float* ws = (float*)d_ws;
    float*     pp1   = ws;                           // 32768
    float*     pp2   = ws + 32768;                   // 32768
    _Float16*  fragB = (_Float16*)(ws + 65536);      // 262144 halves
    _Float16*  fragA = (_Float16*)(ws + 196608);     // 262144 halves
    float*     regp  = ws + 327680;                  // 8192

    kA_prep<<<ROWS_TOT / 64, 64, 0, stream>>>(pts, f1, f2, pp1, pp2,
                                              fragA, fragB, regp, out);
    kB_main<<<NTILE, 1024, 0, stream>>>(pp1, pp2, fragA, fragB, regp, wg, out);
}

// Round 8
// 33.816 us; speedup vs baseline: 1.0389x; 1.0389x over previous
//
#include <hip/hip_runtime.h>
#include <math.h>

// DeepFeatureLoss: B=2, N=4096, D=32, fp32 in/out.
// out[0..1] = ce_loss[b], out[2..3] = reg_loss[b].
//
// ce_i = log(s_f) - t/s_p   (softmax max pinned at 0; both dists <= 0):
//   s_p = sum_j exp(pd_ij), t = sum_j exp(pd_ij)*fd_ij, s_f = sum_j exp(fd_ij)
// exp2 folding: points *PSC, features *FSC, norms *L2E -> bare v_exp_f32;
// t in log2 units -> *LN2 at finalize.
//
// R8: TCP/VMEM-instruction relief. kB blocks = (i-group of 8 tiles) x
// (j-segment of 32 tiles). 8 waves share each staged j-tile: bfrag via
// 2-slot LDS ring (rotating stager wave, 1 barrier/iter, disjoint slots),
// pw pre-staged 8KB. VMEM wave-instrs: 262K -> ~40K. Row sums combined
// across the 8 j-segment blocks via atomicAdd planes + k2 (no fences).
//
// ws (floats): pp1[0,32768) pp2[32768,65536) fragB[65536,196608)
// fragA[196608,327680) regp[327680,335872) accS[335872) accT[344064)
// accF[352256) ; total 360448 floats (~1.44 MB).

#define NPTS 4096
#define ROWS_TOT 8192
#define DF 32
#define JT_PER 32                // j-tiles per block (j-segment)
#define NSEG 8                   // j-segments per batch (8*32=256 tiles)

#define L2E  1.4426950408889634f
#define LN2  0.6931471805599453f
#define FSC  1.6986436f          // sqrt(2*log2e)
#define PSC  240.2244f           // 200*sqrt(log2e)

typedef _Float16 half8 __attribute__((ext_vector_type(8)));
typedef float f4 __attribute__((ext_vector_type(4)));

// ---- kA: prep + zero acc planes ----
__global__ void kA_prep(const float* __restrict__ pts,
                        const float* __restrict__ f1g,
                        const float* __restrict__ f2g,
                        float* __restrict__ pp1, float* __restrict__ pp2,
                        _Float16* __restrict__ fragA, _Float16* __restrict__ fragB,
                        float* __restrict__ regp,
                        float* __restrict__ accS, float* __restrict__ accT,
                        float* __restrict__ accF, float* __restrict__ out) {
    const int r = blockIdx.x * 64 + threadIdx.x;     // 0..8191
    accS[r] = 0.0f; accT[r] = 0.0f; accF[r] = 0.0f;
    if (r < 4) out[r] = 0.0f;
    const int jt = r >> 4;                           // global tile id 0..511
    const int c  = r & 15;                           // row/col within tile

    float n1, n2, reg1, reg2;
    {
        const float4* f2v = (const float4*)(f2g + (size_t)r * DF);
        float vals[32];
        float s = 0.0f;
#pragma unroll
        for (int q = 0; q < 8; ++q) {
            float4 v = f2v[q];
            vals[4*q]=v.x; vals[4*q+1]=v.y; vals[4*q+2]=v.z; vals[4*q+3]=v.w;
            s += v.x*v.x + v.y*v.y + v.z*v.z + v.w*v.w;
        }
        n2 = s;
        reg2 = s - vals[0]*vals[0] - vals[1]*vals[1] - vals[2]*vals[2];
        half8* fv = (half8*)fragB;
#pragma unroll
        for (int kb = 0; kb < 4; ++kb) {             // lane-ordered slot
            half8 h;
#pragma unroll
            for (int i = 0; i < 8; ++i) h[i] = (_Float16)(vals[kb*8+i] * FSC);
            fv[(size_t)jt*64 + kb*16 + c] = h;
        }
    }
    {
        const float4* f1v = (const float4*)(f1g + (size_t)r * DF);
        float vals[32];
        float s = 0.0f;
#pragma unroll
        for (int q = 0; q < 8; ++q) {
            float4 v = f1v[q];
            vals[4*q]=v.x; vals[4*q+1]=v.y; vals[4*q+2]=v.z; vals[4*q+3]=v.w;
            s += v.x*v.x + v.y*v.y + v.z*v.z + v.w*v.w;
        }
        n1 = s;
        reg1 = s - vals[0]*vals[0] - vals[1]*vals[1] - vals[2]*vals[2];
        half8* fv = (half8*)fragA;
#pragma unroll
        for (int kb = 0; kb < 4; ++kb) {
            half8 h;
#pragma unroll
            for (int i = 0; i < 8; ++i) h[i] = (_Float16)(vals[kb*8+i] * FSC);
            fv[(size_t)jt*64 + kb*16 + c] = h;
        }
    }
    const float* pp = pts + (size_t)r * 3;
    const float px = pp[0]*PSC, py = pp[1]*PSC, pz = pp[2]*PSC;
    ((float4*)pp1)[r] = make_float4(px, py, pz, n1 * L2E);
    ((float4*)pp2)[r] = make_float4(px, py, pz, n2 * L2E);
    regp[r] = reg1 + reg2;
}

// ---- kB: 8 waves share LDS-staged j-tiles; atomic row-sum planes ----
__launch_bounds__(512, 4)
__global__ void kB_main(const float* __restrict__ pp1,
                        const float* __restrict__ pp2,
                        const _Float16* __restrict__ fragA,
                        const _Float16* __restrict__ fragB,
                        float* __restrict__ accS, float* __restrict__ accT,
                        float* __restrict__ accF) {
    __shared__ half8  bufB[2][64];          // 2 KB ring: one 16x32 f16 tile/slot
    __shared__ float4 pwS[JT_PER * 16];     // 8 KB: all 512 pw rows of the segment

    const int tid = threadIdx.x;
    const int l = tid & 63, wv = tid >> 6;           // wave 0..7
    const int ig = blockIdx.x >> 3;                  // i-group 0..63
    const int js = blockIdx.x & 7;                   // j-segment 0..7
    const int i_tile = ig * 8 + wv;                  // 0..511
    const int b = i_tile >> 8;
    const int i0g = i_tile * 16;
    const int lr = l & 15, lk = l >> 4;

    const int jt0   = b * 256 + js * JT_PER;         // first global j-tile
    const int jrow0 = b * NPTS + js * (JT_PER * 16); // first pw row

    const half8* fragv = (const half8*)fragB;
    const half8 afrag = ((const half8*)fragA)[(size_t)i_tile * 64 + l];

    const int rbase = i0g + lk * 4;                  // this lane's 4 rows
    const float4 q0 = ((const float4*)pp1)[rbase + 0];
    const float4 q1 = ((const float4*)pp1)[rbase + 1];
    const float4 q2 = ((const float4*)pp1)[rbase + 2];
    const float4 q3 = ((const float4*)pp1)[rbase + 3];
    const f4 qx = {q0.x, q1.x, q2.x, q3.x};
    const f4 qy = {q0.y, q1.y, q2.y, q3.y};
    const f4 qz = {q0.z, q1.z, q2.z, q3.z};
    const f4 qw = {q0.w, q1.w, q2.w, q3.w};

    // prologue: stage all pw rows (coalesced, 1 float4/thread) + tile 0
    pwS[tid] = ((const float4*)pp2)[jrow0 + tid];
    if (wv == 0) bufB[0][l] = fragv[(size_t)jt0 * 64 + l];
    __syncthreads();

    f4 sp = {0,0,0,0}, tA = {0,0,0,0}, sf = {0,0,0,0};
    const f4 zero = {0.f, 0.f, 0.f, 0.f};

#pragma unroll 4
    for (int t = 0; t < JT_PER; ++t) {
        const int nt = t + 1;
        const bool stager = (nt < JT_PER) && (wv == (nt & 7));
        half8 nreg;
        if (stager) nreg = fragv[(size_t)(jt0 + nt) * 64 + l];

        const half8  bf = bufB[t & 1][l];
        const float4 pw = pwS[t * 16 + lr];
        const f4 cc4 = __builtin_amdgcn_mfma_f32_16x16x32_f16(afrag, bf, zero, 0, 0, 0);
        const f4 fd = cc4 - qw - pw.w;               // log2e * fea_dist2 (<=0)
        const f4 dx = qx - pw.x;
        const f4 dy = qy - pw.y;
        const f4 dz = qz - pw.z;
        const f4 s  = dx*dx + dy*dy + dz*dz;         // log2e * |dp|^2
        f4 ep, ef;
#pragma unroll
        for (int e = 0; e < 4; ++e) {
            ep[e] = __builtin_amdgcn_exp2f(-s[e]);
            ef[e] = __builtin_amdgcn_exp2f(fd[e]);
        }
        sp += ep;
        tA += ep * fd;
        sf += ef;

        if (stager) bufB[nt & 1][l] = nreg;          // disjoint slot; RAW via barrier
        __syncthreads();
    }

    // reduce over the 16 columns (lane bits 0..3)
#pragma unroll
    for (int m = 1; m < 16; m <<= 1) {
#pragma unroll
        for (int e = 0; e < 4; ++e) {
            sp[e] += __shfl_xor(sp[e], m);
            tA[e] += __shfl_xor(tA[e], m);
            sf[e] += __shfl_xor(sf[e], m);
        }
    }
    if (lr == 0) {
#pragma unroll
        for (int e = 0; e < 4; ++e) {
            atomicAdd(&accS[rbase + e], sp[e]);
            atomicAdd(&accT[rbase + e], tA[e]);
            atomicAdd(&accF[rbase + e], sf[e]);
        }
    }
}

// ---- k2: finalize rows -> out ----
__global__ void k2_final(const float* __restrict__ accS,
                         const float* __restrict__ accT,
                         const float* __restrict__ accF,
                         const float* __restrict__ regp,
                         const float* __restrict__ wg,
                         float* __restrict__ out) {
    __shared__ float redc[4], redr[4];
    const int tid = threadIdx.x;
    const int r = blockIdx.x * 256 + tid;
    const int b = r >> 12;

    const float sp_ = accS[r], tp_ = accT[r], sf_ = accF[r];
    const float ce = __logf(sf_) - (tp_ * LN2) / sp_;
    float contrib = wg[r] * ce;
    float rr = regp[r];

#pragma unroll
    for (int off = 32; off > 0; off >>= 1) {
        contrib += __shfl_down(contrib, off);
        rr      += __shfl_down(rr, off);
    }
    const int wave = tid >> 6, lane = tid & 63;
    if (lane == 0) { redc[wave] = contrib; redr[wave] = rr; }
    __syncthreads();
    if (tid == 0) {
        atomicAdd(&out[b],     redc[0] + redc[1] + redc[2] + redc[3]);
        atomicAdd(&out[2 + b], (redr[0] + redr[1] + redr[2] + redr[3])
                               * (1.0f / (29.0f * (float)NPTS)));
    }
}

extern "C" void kernel_launch(void* const* d_in, const int* in_sizes, int n_in,
                              void* d_out, int out_size, void* d_ws, size_t ws_size,
                              hipStream_t stream) {
    const float* pts = (const float*)d_in[0];
    const float* f1  = (const float*)d_in[1];
    const float* f2  = (const float*)d_in[2];
    const float* wg  = (const float*)d_in[3];
    float* out = (float*)d_out;

    float* ws = (float*)d_ws;
    float*     pp1   = ws;                           // 32768
    float*     pp2   = ws + 32768;                   // 32768
    _Float16*  fragB = (_Float16*)(ws + 65536);      // 262144 halves
    _Float16*  fragA = (_Float16*)(ws + 196608);     // 262144 halves
    float*     regp  = ws + 327680;                  // 8192
    float*     accS  = ws + 335872;                  // 8192
    float*     accT  = ws + 344064;                  // 8192
    float*     accF  = ws + 352256;                  // 8192

    kA_prep<<<ROWS_TOT / 64, 64, 0, stream>>>(pts, f1, f2, pp1, pp2,
                                              fragA, fragB, regp,
                                              accS, accT, accF, out);
    kB_main<<<512, 512, 0, stream>>>(pp1, pp2, fragA, fragB, accS, accT, accF);
    k2_final<<<ROWS_TOT / 256, 256, 0, stream>>>(accS, accT, accF, regp, wg, out);
}